// Round 6
// baseline (630.920 us; speedup 1.0000x reference)
//
#include <hip/hip_runtime.h>

// Problem constants
#define B_ 4
#define S_ 2048
#define D_ 1024
#define H_ 16
#define HD_ 64
#define F_ 4096
#define M_ (B_*S_)   // 8192 tokens

// dtypes (established r2-r5): d_in = float32, d_out = FLOAT32 (reference
// output dtype; the "(bf16" in the test label is only the threshold mode).

typedef __attribute__((ext_vector_type(8))) short bf16x8;   // 8 bf16 (4 VGPR) MFMA A/B frag
typedef __attribute__((ext_vector_type(4))) short short4_t; // 4 bf16 (8B)
typedef __attribute__((ext_vector_type(4))) float f32x4;    // MFMA C/D frag

__device__ __forceinline__ float bf2f(short u) {
    union { unsigned int i; float f; } v;
    v.i = ((unsigned int)(unsigned short)u) << 16;
    return v.f;
}
__device__ __forceinline__ short f2bf(float f) {
    union { float f; unsigned int i; } v; v.f = f;
    unsigned int r = v.i + 0x7fffu + ((v.i >> 16) & 1u);  // RNE
    return (short)(r >> 16);
}

// ---------------------------------------------------------------------------
// fp32 -> bf16 convert (grid-stride, float4 loads)
// ---------------------------------------------------------------------------
__global__ __launch_bounds__(256) void cvt_f2b_k(
    const float* __restrict__ in, short* __restrict__ out, long n)
{
    long i = ((long)blockIdx.x * 256 + threadIdx.x) * 4;
    long stride = (long)gridDim.x * 256 * 4;
    for (; i < n; i += stride) {
        float4 v = *(const float4*)(in + i);
        short4_t o;
        o[0] = f2bf(v.x); o[1] = f2bf(v.y); o[2] = f2bf(v.z); o[3] = f2bf(v.w);
        *(short4_t*)(out + i) = o;
    }
}

// ---------------------------------------------------------------------------
// Tiled transpose: out[z][c][r] = cvt(in[base(z) + r*in_rstride + c])
// base(z) = (z>>4)*in_bstrideB + (z&15)*in_bstrideH ; out base = z*out_bstride
// ---------------------------------------------------------------------------
template<typename TI>
__global__ __launch_bounds__(256) void transpose_k(
    const TI* __restrict__ in, short* __restrict__ out,
    int rows, long in_rstride,
    long in_bstrideB, long in_bstrideH, long out_bstride)
{
    __shared__ short tile[32][33];
    int z = blockIdx.z;
    const TI* ip = in + (long)(z >> 4) * in_bstrideB + (long)(z & 15) * in_bstrideH;
    short* op = out + (long)z * out_bstride;
    int r0 = blockIdx.y * 32, c0 = blockIdx.x * 32;
    int tx = threadIdx.x & 31, ty = threadIdx.x >> 5;   // ty 0..7
#pragma unroll
    for (int i = 0; i < 32; i += 8) {
        TI v = ip[(long)(r0 + ty + i) * in_rstride + (c0 + tx)];
        if constexpr (sizeof(TI) == 4) tile[ty + i][tx] = f2bf((float)v);
        else                           tile[ty + i][tx] = (short)v;
    }
    __syncthreads();
#pragma unroll
    for (int i = 0; i < 32; i += 8)
        op[(long)(c0 + ty + i) * rows + (r0 + tx)] = tile[tx][ty + i];
}

// ---------------------------------------------------------------------------
// GEMM: C[M][N] = act( (A[M][K] @ BT[N][K]^T + bias[N]) * scale )
// A, BT bf16 (k-contiguous); bias fp32. 128x128 tile, BK=32, 4 waves (2x2),
// 16x16x32 bf16 MFMA.  (structure = ref-checked m92 ladder kernel)
// ---------------------------------------------------------------------------
__global__ __launch_bounds__(256) void gemm_k(
    const short* __restrict__ A,    // [M][K] bf16
    const short* __restrict__ BT,   // [N][K] bf16
    const float* __restrict__ bias, // [N] fp32
    short* __restrict__ C,          // [M][N] bf16
    int M, int N, int K, float scale, int relu)
{
    __shared__ short Alds[128][40];
    __shared__ short Blds[128][40];
    int tid = threadIdx.x;
    int wave = tid >> 6, lane = tid & 63;
    int lgrp = lane >> 4, lrow = lane & 15;
    int wr = wave >> 1, wc = wave & 1;
    int bm = blockIdx.y * 128, bn = blockIdx.x * 128;

    f32x4 acc[4][4] = {};
    for (int k0 = 0; k0 < K; k0 += 32) {
        {
            int v = tid;
            int r = v >> 2, kc = (v & 3) * 8;
            *(bf16x8*)&Alds[r][kc] = *(const bf16x8*)(A  + (long)(bm + r) * K + k0 + kc);
            *(bf16x8*)&Blds[r][kc] = *(const bf16x8*)(BT + (long)(bn + r) * K + k0 + kc);
            v = tid + 256;
            r = v >> 2; kc = (v & 3) * 8;
            *(bf16x8*)&Alds[r][kc] = *(const bf16x8*)(A  + (long)(bm + r) * K + k0 + kc);
            *(bf16x8*)&Blds[r][kc] = *(const bf16x8*)(BT + (long)(bn + r) * K + k0 + kc);
        }
        __syncthreads();
        bf16x8 af[4], bv[4];
#pragma unroll
        for (int i = 0; i < 4; i++) {
            af[i] = *(const bf16x8*)&Alds[wr*64 + i*16 + lrow][8*lgrp];
            bv[i] = *(const bf16x8*)&Blds[wc*64 + i*16 + lrow][8*lgrp];
        }
#pragma unroll
        for (int mi = 0; mi < 4; mi++)
#pragma unroll
            for (int ni = 0; ni < 4; ni++)
                acc[mi][ni] = __builtin_amdgcn_mfma_f32_16x16x32_bf16(
                    af[mi], bv[ni], acc[mi][ni], 0, 0, 0);
        __syncthreads();
    }
#pragma unroll
    for (int ni = 0; ni < 4; ni++) {
        int col = bn + wc*64 + ni*16 + lrow;
        float bb = bias[col];
#pragma unroll
        for (int mi = 0; mi < 4; mi++) {
#pragma unroll
            for (int j = 0; j < 4; j++) {
                int row = bm + wr*64 + mi*16 + lgrp*4 + j;
                float v = (acc[mi][ni][j] + bb) * scale;
                if (relu) v = fmaxf(v, 0.0f);
                C[(long)row * N + col] = f2bf(v);
            }
        }
    }
}

// ---------------------------------------------------------------------------
// Flash attention (non-causal). Grid: (q-tiles=32, bh=64). 256 thr = 4 waves.
// Each wave owns 16 Q rows; loops over 64-key tiles with online softmax.
// Q pre-scaled by 1/8 in the QKV GEMM. VT is [bh][e=64][s=2048].
// (exonerated r3<->r4: identical output vs naive fp32 attention)
// ---------------------------------------------------------------------------
__global__ __launch_bounds__(256) void attn_k(
    const short* __restrict__ Q,   // [M][1024]  (h*64+e cols), scaled
    const short* __restrict__ Kb,  // [M][1024]
    const short* __restrict__ VT,  // [64][64][2048]
    short* __restrict__ O)         // [M][1024]
{
    __shared__ short Klds[64][72];      // [key][e]
    __shared__ short Vlds[64][72];      // [e][key]
    __shared__ short Plds[4][16][72];   // per-wave P round-trip
    int bh = blockIdx.y, b = bh >> 4, h = bh & 15;
    int q0 = blockIdx.x * 64;
    int tid = threadIdx.x, wave = tid >> 6, lane = tid & 63;
    int lgrp = lane >> 4, lrow = lane & 15;

    bf16x8 aq[2];
    {
        const short* qp = Q + (long)(b*S_ + q0 + wave*16 + lrow) * 1024 + h*64 + 8*lgrp;
        aq[0] = *(const bf16x8*)qp;
        aq[1] = *(const bf16x8*)(qp + 32);
    }
    f32x4 acco[4] = {};
    float mj[4] = {-1e30f, -1e30f, -1e30f, -1e30f};
    float lj[4] = {0.f, 0.f, 0.f, 0.f};

    const short* kbase = Kb + (long)(b*S_) * 1024 + h*64;
    const short* vbase = VT + (long)bh * (64L*S_);

    for (int kb = 0; kb < S_; kb += 64) {
        {   // stage K [key][e] and V^T [e][key] — all vector b128
            int v = tid;
            int a = v >> 3, cc = (v & 7) * 8;
            *(bf16x8*)&Klds[a][cc] = *(const bf16x8*)(kbase + (long)(kb + a)*1024 + cc);
            *(bf16x8*)&Vlds[a][cc] = *(const bf16x8*)(vbase + (long)a * S_ + kb + cc);
            v = tid + 256;
            a = v >> 3; cc = (v & 7) * 8;
            *(bf16x8*)&Klds[a][cc] = *(const bf16x8*)(kbase + (long)(kb + a)*1024 + cc);
            *(bf16x8*)&Vlds[a][cc] = *(const bf16x8*)(vbase + (long)a * S_ + kb + cc);
        }
        __syncthreads();

        f32x4 accs[4] = {};
#pragma unroll
        for (int cb = 0; cb < 4; cb++) {
#pragma unroll
            for (int kk = 0; kk < 2; kk++) {
                bf16x8 bk = *(const bf16x8*)&Klds[cb*16 + lrow][kk*32 + 8*lgrp];
                accs[cb] = __builtin_amdgcn_mfma_f32_16x16x32_bf16(aq[kk], bk, accs[cb], 0, 0, 0);
            }
        }
#pragma unroll
        for (int j = 0; j < 4; j++) {
            float mx = fmaxf(fmaxf(accs[0][j], accs[1][j]), fmaxf(accs[2][j], accs[3][j]));
#pragma unroll
            for (int off = 1; off < 16; off <<= 1)
                mx = fmaxf(mx, __shfl_xor(mx, off));
            float mnew = fmaxf(mj[j], mx);
            float alpha = __expf(mj[j] - mnew);
            mj[j] = mnew;
            float sum = 0.f;
#pragma unroll
            for (int cb = 0; cb < 4; cb++) {
                float p = __expf(accs[cb][j] - mnew);
                accs[cb][j] = p;
                sum += p;
            }
#pragma unroll
            for (int off = 1; off < 16; off <<= 1)
                sum += __shfl_xor(sum, off);
            lj[j] = lj[j] * alpha + sum;
#pragma unroll
            for (int eb = 0; eb < 4; eb++) acco[eb][j] *= alpha;
        }
#pragma unroll
        for (int cb = 0; cb < 4; cb++)
#pragma unroll
            for (int j = 0; j < 4; j++)
                Plds[wave][lgrp*4 + j][cb*16 + lrow] = f2bf(accs[cb][j]);
        __syncthreads();
        bf16x8 ap0 = *(const bf16x8*)&Plds[wave][lrow][8*lgrp];
        bf16x8 ap1 = *(const bf16x8*)&Plds[wave][lrow][32 + 8*lgrp];
#pragma unroll
        for (int eb = 0; eb < 4; eb++) {
            bf16x8 bv0 = *(const bf16x8*)&Vlds[eb*16 + lrow][8*lgrp];
            bf16x8 bv1 = *(const bf16x8*)&Vlds[eb*16 + lrow][32 + 8*lgrp];
            acco[eb] = __builtin_amdgcn_mfma_f32_16x16x32_bf16(ap0, bv0, acco[eb], 0, 0, 0);
            acco[eb] = __builtin_amdgcn_mfma_f32_16x16x32_bf16(ap1, bv1, acco[eb], 0, 0, 0);
        }
        __syncthreads();
    }
#pragma unroll
    for (int eb = 0; eb < 4; eb++) {
#pragma unroll
        for (int j = 0; j < 4; j++) {
            int qr = q0 + wave*16 + lgrp*4 + j;
            O[(long)(b*S_ + qr)*1024 + h*64 + eb*16 + lrow] = f2bf(acco[eb][j] / lj[j]);
        }
    }
}

// ---------------------------------------------------------------------------
// Residual + LayerNorm: O[row] = LN(X[row] + Y[row]) * g + be   (D=1024)
// XF32: X fp32 (original x) else bf16.  OUTF32: O fp32 (d_out) else bf16.
// ---------------------------------------------------------------------------
template<int XF32, int OUTF32>
__global__ __launch_bounds__(256) void ln_k(
    const void* __restrict__ Xv, const short* __restrict__ Y,
    const float* __restrict__ g, const float* __restrict__ be,
    void* __restrict__ Ov)
{
    int row = blockIdx.x, tid = threadIdx.x;
    long base = (long)row * 1024 + tid * 4;
    float a[4];
    if constexpr (XF32) {
        float4 xv = *(const float4*)((const float*)Xv + base);
        a[0] = xv.x; a[1] = xv.y; a[2] = xv.z; a[3] = xv.w;
    } else {
        short4_t xv = *(const short4_t*)((const short*)Xv + base);
#pragma unroll
        for (int j = 0; j < 4; j++) a[j] = bf2f(xv[j]);
    }
    short4_t yv = *(const short4_t*)(Y + base);
    float s = 0.f, s2 = 0.f;
#pragma unroll
    for (int j = 0; j < 4; j++) {
        a[j] += bf2f(yv[j]);
        s += a[j]; s2 += a[j] * a[j];
    }
#pragma unroll
    for (int off = 32; off >= 1; off >>= 1) {
        s  += __shfl_xor(s, off);
        s2 += __shfl_xor(s2, off);
    }
    __shared__ float red[8];
    if ((tid & 63) == 0) { red[(tid >> 6)*2] = s; red[(tid >> 6)*2 + 1] = s2; }
    __syncthreads();
    s  = red[0] + red[2] + red[4] + red[6];
    s2 = red[1] + red[3] + red[5] + red[7];
    float mean = s * (1.0f/1024.0f);
    float var  = s2 * (1.0f/1024.0f) - mean*mean;
    float rstd = rsqrtf(var + 1e-5f);
    float4 gv = *(const float4*)(g  + tid*4);
    float4 bv = *(const float4*)(be + tid*4);
    float r0 = (a[0] - mean) * rstd * gv.x + bv.x;
    float r1 = (a[1] - mean) * rstd * gv.y + bv.y;
    float r2 = (a[2] - mean) * rstd * gv.z + bv.z;
    float r3 = (a[3] - mean) * rstd * gv.w + bv.w;
    if constexpr (OUTF32) {
        *(float4*)((float*)Ov + base) = make_float4(r0, r1, r2, r3);
    } else {
        short4_t ov;
        ov[0] = f2bf(r0); ov[1] = f2bf(r1); ov[2] = f2bf(r2); ov[3] = f2bf(r3);
        *(short4_t*)((short*)Ov + base) = ov;
    }
}

// ---------------------------------------------------------------------------
extern "C" void kernel_launch(void* const* d_in, const int* in_sizes, int n_in,
                              void* d_out, int out_size, void* d_ws, size_t ws_size,
                              hipStream_t stream)
{
    // Input order: insertion order confirmed (r5: identity branch taken,
    // output identical to r3). Keep sorted-order fallback as dead insurance.
    static const int ins[17] = {0,1,2,3,4,5,6,7,8,9,10,11,12,13,14,15,16};
    static const int srt[17] = {16,4,12,2,10,5,13,3,11,0,6,1,7,14,8,15,9};
    const int* IX = (in_sizes[0] == 8388608) ? ins : srt;

    const float* x   = (const float*)d_in[IX[0]];
    const float* Wq  = (const float*)d_in[IX[1]];
    const float* bq  = (const float*)d_in[IX[2]];
    const float* Wk  = (const float*)d_in[IX[3]];
    const float* bk  = (const float*)d_in[IX[4]];
    const float* Wv  = (const float*)d_in[IX[5]];
    const float* bv  = (const float*)d_in[IX[6]];
    const float* Wo  = (const float*)d_in[IX[7]];
    const float* bo  = (const float*)d_in[IX[8]];
    const float* W1  = (const float*)d_in[IX[9]];
    const float* b1  = (const float*)d_in[IX[10]];
    const float* W2  = (const float*)d_in[IX[11]];
    const float* b2  = (const float*)d_in[IX[12]];
    const float* g1  = (const float*)d_in[IX[13]];
    const float* be1 = (const float*)d_in[IX[14]];
    const float* g2  = (const float*)d_in[IX[15]];
    const float* be2 = (const float*)d_in[IX[16]];
    short* ws  = (short*)d_ws;

    // Compact workspace overlay (short-element offsets). Peak = 126 MB.
    short* Qb  = ws + 0L;
    short* Kbf = ws + 8388608L;
    short* xb  = ws + 16777216L;
    short* VTb = ws + 25165824L;
    short* ctx = ws + 33554432L;
    short* WqT = ws + 41943040L;
    short* WkT = ws + 42991616L;
    short* WvT = ws + 44040192L;
    short* WoT = ws + 45088768L;
    short* Vbf = ws + 46137344L;
    short* W1T = ws + 54525952L;
    short* W2T = ws + 58720256L;
    short* hb  = ws + 16777216L;  // [16M,48M) 32M elem — xb/VTb/ctx dead by FFN1
    short* ao  = ws + 0L;         // reuses Qb (dead after attn)
    short* x1  = ws + 8388608L;   // reuses Kbf (dead after attn)
    short* ffn = ws + 0L;         // reuses ao (dead after ln1)

    dim3 blk(256);

    // x -> bf16
    cvt_f2b_k<<<2048, blk, 0, stream>>>(x, xb, (long)M_ * D_);

    // Weight transposes (fp32 -> bf16): everything becomes [N][K] k-contiguous
    transpose_k<float><<<dim3(2, 32, 16),  blk, 0, stream>>>(Wq, WqT, 1024, 64,   0, 65536, 65536);
    transpose_k<float><<<dim3(2, 32, 16),  blk, 0, stream>>>(Wk, WkT, 1024, 64,   0, 65536, 65536);
    transpose_k<float><<<dim3(2, 32, 16),  blk, 0, stream>>>(Wv, WvT, 1024, 64,   0, 65536, 65536);
    transpose_k<float><<<dim3(32, 32, 1),  blk, 0, stream>>>(Wo, WoT, 1024, 1024, 0, 0, 0);
    transpose_k<float><<<dim3(128, 32, 1), blk, 0, stream>>>(W1, W1T, 1024, 4096, 0, 0, 0);
    transpose_k<float><<<dim3(32, 128, 1), blk, 0, stream>>>(W2, W2T, 4096, 1024, 0, 0, 0);

    // QKV projections (Q gets softmax scale 1/8 folded in, after bias)
    gemm_k<<<dim3(8, 64), blk, 0, stream>>>(xb, WqT, bq, Qb,  M_, 1024, 1024, 0.125f, 0);
    gemm_k<<<dim3(8, 64), blk, 0, stream>>>(xb, WkT, bk, Kbf, M_, 1024, 1024, 1.0f,   0);
    gemm_k<<<dim3(8, 64), blk, 0, stream>>>(xb, WvT, bv, Vbf, M_, 1024, 1024, 1.0f,   0);

    // V -> V^T per (b,h): [2048 s][64 e] -> [64 e][2048 s]
    transpose_k<short><<<dim3(2, 64, 64), blk, 0, stream>>>(Vbf, VTb, 2048, 1024, 2097152, 64, 131072);

    // flash attention
    attn_k<<<dim3(32, 64), blk, 0, stream>>>(Qb, Kbf, VTb, ctx);

    // out projection + residual LN (residual from ORIGINAL fp32 x)
    gemm_k<<<dim3(8, 64), blk, 0, stream>>>(ctx, WoT, bo, ao, M_, 1024, 1024, 1.0f, 0);
    ln_k<1,0><<<8192, blk, 0, stream>>>(x, ao, g1, be1, x1);

    // FFN
    gemm_k<<<dim3(32, 64), blk, 0, stream>>>(x1, W1T, b1, hb,  M_, 4096, 1024, 1.0f, 1);
    gemm_k<<<dim3(8, 64),  blk, 0, stream>>>(hb, W2T, b2, ffn, M_, 1024, 4096, 1.0f, 0);

    // final LN -> fp32 d_out
    ln_k<0,1><<<8192, blk, 0, stream>>>(x1, ffn, g2, be2, d_out);
}

// Round 7
// 618.094 us; speedup vs baseline: 1.0208x; 1.0208x over previous
//
#include <hip/hip_runtime.h>

// Problem constants
#define B_ 4
#define S_ 2048
#define D_ 1024
#define H_ 16
#define HD_ 64
#define F_ 4096
#define M_ (B_*S_)   // 8192 tokens

// dtypes (established r2-r6): d_in = float32, d_out = float32.

typedef __attribute__((ext_vector_type(8))) short bf16x8;   // 8 bf16 (4 VGPR) MFMA A/B frag
typedef __attribute__((ext_vector_type(4))) short short4_t; // 4 bf16 (8B)
typedef __attribute__((ext_vector_type(4))) float f32x4;    // MFMA C/D frag

#define AS1q __attribute__((address_space(1)))
#define AS3q __attribute__((address_space(3)))

__device__ __forceinline__ float bf2f(short u) {
    union { unsigned int i; float f; } v;
    v.i = ((unsigned int)(unsigned short)u) << 16;
    return v.f;
}
__device__ __forceinline__ short f2bf(float f) {
    union { float f; unsigned int i; } v; v.f = f;
    unsigned int r = v.i + 0x7fffu + ((v.i >> 16) & 1u);  // RNE
    return (short)(r >> 16);
}
// async global->LDS, 16B per lane; LDS dest must be wave-uniform base (lane*16 auto)
__device__ __forceinline__ void gld_lds16(const short* g, short* l) {
    __builtin_amdgcn_global_load_lds((const AS1q void*)g, (AS3q void*)l, 16, 0, 0);
}

// ---------------------------------------------------------------------------
// fp32 -> bf16 convert (grid-stride, float4 loads)
// ---------------------------------------------------------------------------
__global__ __launch_bounds__(256) void cvt_f2b_k(
    const float* __restrict__ in, short* __restrict__ out, long n)
{
    long i = ((long)blockIdx.x * 256 + threadIdx.x) * 4;
    long stride = (long)gridDim.x * 256 * 4;
    for (; i < n; i += stride) {
        float4 v = *(const float4*)(in + i);
        short4_t o;
        o[0] = f2bf(v.x); o[1] = f2bf(v.y); o[2] = f2bf(v.z); o[3] = f2bf(v.w);
        *(short4_t*)(out + i) = o;
    }
}

// ---------------------------------------------------------------------------
// Tiled transpose: out[z][c][r] = cvt(in[base(z) + r*in_rstride + c])
// ---------------------------------------------------------------------------
template<typename TI>
__global__ __launch_bounds__(256) void transpose_k(
    const TI* __restrict__ in, short* __restrict__ out,
    int rows, long in_rstride,
    long in_bstrideB, long in_bstrideH, long out_bstride)
{
    __shared__ short tile[32][33];
    int z = blockIdx.z;
    const TI* ip = in + (long)(z >> 4) * in_bstrideB + (long)(z & 15) * in_bstrideH;
    short* op = out + (long)z * out_bstride;
    int r0 = blockIdx.y * 32, c0 = blockIdx.x * 32;
    int tx = threadIdx.x & 31, ty = threadIdx.x >> 5;   // ty 0..7
#pragma unroll
    for (int i = 0; i < 32; i += 8) {
        TI v = ip[(long)(r0 + ty + i) * in_rstride + (c0 + tx)];
        if constexpr (sizeof(TI) == 4) tile[ty + i][tx] = f2bf((float)v);
        else                           tile[ty + i][tx] = (short)v;
    }
    __syncthreads();
#pragma unroll
    for (int i = 0; i < 32; i += 8)
        op[(long)(c0 + ty + i) * rows + (r0 + tx)] = tile[tx][ty + i];
}

// ---------------------------------------------------------------------------
// GEMM (m97 structure): C = act((A @ BT^T + bias) * scale)
// 128x128 tile, BK=32, 4 waves, global_load_lds width-16 staging, linear LDS.
// ---------------------------------------------------------------------------
__global__ __launch_bounds__(256) void gemm_k(
    const short* __restrict__ A,    // [M][K] bf16
    const short* __restrict__ BT,   // [N][K] bf16
    const float* __restrict__ bias, // [N] fp32
    short* __restrict__ C,          // [M][N] bf16
    int M, int N, int K, float scale, int relu)
{
    __shared__ short Alds[128*32];   // linear, no pad (global_load_lds constraint)
    __shared__ short Blds[128*32];
    int tid = threadIdx.x;
    int wave = tid >> 6, lane = tid & 63;
    int lgrp = lane >> 4, lrow = lane & 15;
    int wr = wave >> 1, wc = wave & 1;
    int bm = blockIdx.y * 128, bn = blockIdx.x * 128;

    // staging: wave w covers rows [w*32, w*32+32), 2 instrs x 16 rows;
    // lane carries row=lane>>2, 16B chunk=lane&3 -> LDS linear lane*16B.
    int srow = wave * 32 + (lane >> 2);
    int scol = (lane & 3) * 8;
    const short* gA = A  + (long)(bm + srow) * K + scol;
    const short* gB = BT + (long)(bn + srow) * K + scol;
    short* lA0 = &Alds[(wave * 32) * 32];
    short* lA1 = &Alds[(wave * 32 + 16) * 32];
    short* lB0 = &Blds[(wave * 32) * 32];
    short* lB1 = &Blds[(wave * 32 + 16) * 32];
    long k16 = 16L * K;

    f32x4 acc[4][4] = {};
    for (int k0 = 0; k0 < K; k0 += 32) {
        gld_lds16(gA + k0,       lA0);
        gld_lds16(gA + k0 + k16, lA1);
        gld_lds16(gB + k0,       lB0);
        gld_lds16(gB + k0 + k16, lB1);
        __syncthreads();   // drains vmcnt -> LDS writes complete
        bf16x8 af[4], bv[4];
#pragma unroll
        for (int i = 0; i < 4; i++) {
            af[i] = *(const bf16x8*)&Alds[(wr*64 + i*16 + lrow) * 32 + 8*lgrp];
            bv[i] = *(const bf16x8*)&Blds[(wc*64 + i*16 + lrow) * 32 + 8*lgrp];
        }
#pragma unroll
        for (int mi = 0; mi < 4; mi++)
#pragma unroll
            for (int ni = 0; ni < 4; ni++)
                acc[mi][ni] = __builtin_amdgcn_mfma_f32_16x16x32_bf16(
                    af[mi], bv[ni], acc[mi][ni], 0, 0, 0);
        __syncthreads();   // all reads done before next-iter staging overwrites
    }
#pragma unroll
    for (int ni = 0; ni < 4; ni++) {
        int col = bn + wc*64 + ni*16 + lrow;
        float bb = bias[col];
#pragma unroll
        for (int mi = 0; mi < 4; mi++) {
#pragma unroll
            for (int j = 0; j < 4; j++) {
                int row = bm + wr*64 + mi*16 + lgrp*4 + j;
                float v = (acc[mi][ni][j] + bb) * scale;
                if (relu) v = fmaxf(v, 0.0f);
                C[(long)row * N + col] = f2bf(v);
            }
        }
    }
}

// ---------------------------------------------------------------------------
// Flash attention, double-buffered, 1 barrier/iter. Grid: (32 q-tiles, 64 bh).
// 4 waves x 16 Q-rows; KVBLK=64; online softmax in exp2 domain (Q pre-scaled
// by 0.125*log2(e) in the QKV GEMM). K/V prefetched into regs (T14) while
// computing the current tile; P round-trip is wave-private (no barrier).
// ---------------------------------------------------------------------------
__global__ __launch_bounds__(256) void attn_k(
    const short* __restrict__ Q,   // [M][1024], scaled by 0.125*log2e
    const short* __restrict__ Kb,  // [M][1024]
    const short* __restrict__ VT,  // [64][64][2048]
    short* __restrict__ O)         // [M][1024]
{
    __shared__ short Klds[2][64][72];   // [buf][key][e]
    __shared__ short Vlds[2][64][72];   // [buf][e][key]
    __shared__ short Plds[4][16][72];   // per-wave P round-trip
    int bh = blockIdx.y, b = bh >> 4, h = bh & 15;
    int q0 = blockIdx.x * 64;
    int tid = threadIdx.x, wave = tid >> 6, lane = tid & 63;
    int lgrp = lane >> 4, lrow = lane & 15;

    bf16x8 aq[2];
    {
        const short* qp = Q + (long)(b*S_ + q0 + wave*16 + lrow) * 1024 + h*64 + 8*lgrp;
        aq[0] = *(const bf16x8*)qp;
        aq[1] = *(const bf16x8*)(qp + 32);
    }
    f32x4 acco[4] = {};
    float mj[4] = {-1e30f, -1e30f, -1e30f, -1e30f};
    float lj[4] = {0.f, 0.f, 0.f, 0.f};

    const short* kbase = Kb + (long)(b*S_) * 1024 + h*64;
    const short* vbase = VT + (long)bh * (64L*S_);

    // staging addressing: thread covers rows sa and sa+32, 8-short chunk sc
    int sa = tid >> 3, sc = (tid & 7) * 8;
    const short* kp0 = kbase + (long)sa * 1024 + sc;
    const short* kp1 = kbase + (long)(sa + 32) * 1024 + sc;
    const short* vp0 = vbase + (long)sa * S_ + sc;
    const short* vp1 = vbase + (long)(sa + 32) * S_ + sc;

    // prologue: tile 0 -> buf 0
    {
        bf16x8 k0r = *(const bf16x8*)kp0, k1r = *(const bf16x8*)kp1;
        bf16x8 v0r = *(const bf16x8*)vp0, v1r = *(const bf16x8*)vp1;
        *(bf16x8*)&Klds[0][sa][sc]      = k0r;
        *(bf16x8*)&Klds[0][sa + 32][sc] = k1r;
        *(bf16x8*)&Vlds[0][sa][sc]      = v0r;
        *(bf16x8*)&Vlds[0][sa + 32][sc] = v1r;
    }

    bf16x8 k0r, k1r, v0r, v1r;
    for (int t = 0; t < 32; ++t) {
        int cur = t & 1;
        __syncthreads();   // buf[cur] visible; prior reads of buf[cur^1] done
        if (t < 31) {      // issue next-tile loads early (latency hidden under compute)
            long ko = (long)(t + 1) * 64 * 1024;
            int  vo = (t + 1) * 64;
            k0r = *(const bf16x8*)(kp0 + ko);
            k1r = *(const bf16x8*)(kp1 + ko);
            v0r = *(const bf16x8*)(vp0 + vo);
            v1r = *(const bf16x8*)(vp1 + vo);
        }

        // scores S = Q K^T
        f32x4 accs[4] = {};
        __builtin_amdgcn_s_setprio(1);
#pragma unroll
        for (int cb = 0; cb < 4; cb++) {
#pragma unroll
            for (int kk = 0; kk < 2; kk++) {
                bf16x8 bk = *(const bf16x8*)&Klds[cur][cb*16 + lrow][kk*32 + 8*lgrp];
                accs[cb] = __builtin_amdgcn_mfma_f32_16x16x32_bf16(aq[kk], bk, accs[cb], 0, 0, 0);
            }
        }
        __builtin_amdgcn_s_setprio(0);

        // online softmax (exp2 domain) per row j
#pragma unroll
        for (int j = 0; j < 4; j++) {
            float mx = fmaxf(fmaxf(accs[0][j], accs[1][j]), fmaxf(accs[2][j], accs[3][j]));
#pragma unroll
            for (int off = 1; off < 16; off <<= 1)
                mx = fmaxf(mx, __shfl_xor(mx, off));
            float mnew = fmaxf(mj[j], mx);
            float alpha = exp2f(mj[j] - mnew);
            mj[j] = mnew;
            float sum = 0.f;
#pragma unroll
            for (int cb = 0; cb < 4; cb++) {
                float p = exp2f(accs[cb][j] - mnew);
                accs[cb][j] = p;
                sum += p;
            }
#pragma unroll
            for (int off = 1; off < 16; off <<= 1)
                sum += __shfl_xor(sum, off);
            lj[j] = lj[j] * alpha + sum;
#pragma unroll
            for (int eb = 0; eb < 4; eb++) acco[eb][j] *= alpha;
        }

        // P: C-layout -> A-layout via wave-private LDS (no barrier needed)
#pragma unroll
        for (int cb = 0; cb < 4; cb++)
#pragma unroll
            for (int j = 0; j < 4; j++)
                Plds[wave][lgrp*4 + j][cb*16 + lrow] = f2bf(accs[cb][j]);
        bf16x8 ap0 = *(const bf16x8*)&Plds[wave][lrow][8*lgrp];
        bf16x8 ap1 = *(const bf16x8*)&Plds[wave][lrow][32 + 8*lgrp];

        // PV
        __builtin_amdgcn_s_setprio(1);
#pragma unroll
        for (int eb = 0; eb < 4; eb++) {
            bf16x8 bv0 = *(const bf16x8*)&Vlds[cur][eb*16 + lrow][8*lgrp];
            bf16x8 bv1 = *(const bf16x8*)&Vlds[cur][eb*16 + lrow][32 + 8*lgrp];
            acco[eb] = __builtin_amdgcn_mfma_f32_16x16x32_bf16(ap0, bv0, acco[eb], 0, 0, 0);
            acco[eb] = __builtin_amdgcn_mfma_f32_16x16x32_bf16(ap1, bv1, acco[eb], 0, 0, 0);
        }
        __builtin_amdgcn_s_setprio(0);

        // write staged regs -> buf[cur^1] (nobody reads it this interval)
        if (t < 31) {
            int nxt = cur ^ 1;
            *(bf16x8*)&Klds[nxt][sa][sc]      = k0r;
            *(bf16x8*)&Klds[nxt][sa + 32][sc] = k1r;
            *(bf16x8*)&Vlds[nxt][sa][sc]      = v0r;
            *(bf16x8*)&Vlds[nxt][sa + 32][sc] = v1r;
        }
    }
#pragma unroll
    for (int eb = 0; eb < 4; eb++) {
#pragma unroll
        for (int j = 0; j < 4; j++) {
            int qr = q0 + wave*16 + lgrp*4 + j;
            O[(long)(b*S_ + qr)*1024 + h*64 + eb*16 + lrow] = f2bf(acco[eb][j] / lj[j]);
        }
    }
}

// ---------------------------------------------------------------------------
// Residual + LayerNorm: O[row] = LN(X[row] + Y[row]) * g + be   (D=1024)
// ---------------------------------------------------------------------------
template<int XF32, int OUTF32>
__global__ __launch_bounds__(256) void ln_k(
    const void* __restrict__ Xv, const short* __restrict__ Y,
    const float* __restrict__ g, const float* __restrict__ be,
    void* __restrict__ Ov)
{
    int row = blockIdx.x, tid = threadIdx.x;
    long base = (long)row * 1024 + tid * 4;
    float a[4];
    if constexpr (XF32) {
        float4 xv = *(const float4*)((const float*)Xv + base);
        a[0] = xv.x; a[1] = xv.y; a[2] = xv.z; a[3] = xv.w;
    } else {
        short4_t xv = *(const short4_t*)((const short*)Xv + base);
#pragma unroll
        for (int j = 0; j < 4; j++) a[j] = bf2f(xv[j]);
    }
    short4_t yv = *(const short4_t*)(Y + base);
    float s = 0.f, s2 = 0.f;
#pragma unroll
    for (int j = 0; j < 4; j++) {
        a[j] += bf2f(yv[j]);
        s += a[j]; s2 += a[j] * a[j];
    }
#pragma unroll
    for (int off = 32; off >= 1; off >>= 1) {
        s  += __shfl_xor(s, off);
        s2 += __shfl_xor(s2, off);
    }
    __shared__ float red[8];
    if ((tid & 63) == 0) { red[(tid >> 6)*2] = s; red[(tid >> 6)*2 + 1] = s2; }
    __syncthreads();
    s  = red[0] + red[2] + red[4] + red[6];
    s2 = red[1] + red[3] + red[5] + red[7];
    float mean = s * (1.0f/1024.0f);
    float var  = s2 * (1.0f/1024.0f) - mean*mean;
    float rstd = rsqrtf(var + 1e-5f);
    float4 gv = *(const float4*)(g  + tid*4);
    float4 bv = *(const float4*)(be + tid*4);
    float r0 = (a[0] - mean) * rstd * gv.x + bv.x;
    float r1 = (a[1] - mean) * rstd * gv.y + bv.y;
    float r2 = (a[2] - mean) * rstd * gv.z + bv.z;
    float r3 = (a[3] - mean) * rstd * gv.w + bv.w;
    if constexpr (OUTF32) {
        *(float4*)((float*)Ov + base) = make_float4(r0, r1, r2, r3);
    } else {
        short4_t ov;
        ov[0] = f2bf(r0); ov[1] = f2bf(r1); ov[2] = f2bf(r2); ov[3] = f2bf(r3);
        *(short4_t*)((short*)Ov + base) = ov;
    }
}

// ---------------------------------------------------------------------------
extern "C" void kernel_launch(void* const* d_in, const int* in_sizes, int n_in,
                              void* d_out, int out_size, void* d_ws, size_t ws_size,
                              hipStream_t stream)
{
    static const int ins[17] = {0,1,2,3,4,5,6,7,8,9,10,11,12,13,14,15,16};
    static const int srt[17] = {16,4,12,2,10,5,13,3,11,0,6,1,7,14,8,15,9};
    const int* IX = (in_sizes[0] == 8388608) ? ins : srt;

    const float* x   = (const float*)d_in[IX[0]];
    const float* Wq  = (const float*)d_in[IX[1]];
    const float* bq  = (const float*)d_in[IX[2]];
    const float* Wk  = (const float*)d_in[IX[3]];
    const float* bk  = (const float*)d_in[IX[4]];
    const float* Wv  = (const float*)d_in[IX[5]];
    const float* bv  = (const float*)d_in[IX[6]];
    const float* Wo  = (const float*)d_in[IX[7]];
    const float* bo  = (const float*)d_in[IX[8]];
    const float* W1  = (const float*)d_in[IX[9]];
    const float* b1  = (const float*)d_in[IX[10]];
    const float* W2  = (const float*)d_in[IX[11]];
    const float* b2  = (const float*)d_in[IX[12]];
    const float* g1  = (const float*)d_in[IX[13]];
    const float* be1 = (const float*)d_in[IX[14]];
    const float* g2  = (const float*)d_in[IX[15]];
    const float* be2 = (const float*)d_in[IX[16]];
    short* ws  = (short*)d_ws;

    // Compact workspace overlay (short-element offsets). Peak = 126 MB.
    short* Qb  = ws + 0L;
    short* Kbf = ws + 8388608L;
    short* xb  = ws + 16777216L;
    short* VTb = ws + 25165824L;
    short* ctx = ws + 33554432L;
    short* WqT = ws + 41943040L;
    short* WkT = ws + 42991616L;
    short* WvT = ws + 44040192L;
    short* WoT = ws + 45088768L;
    short* Vbf = ws + 46137344L;
    short* W1T = ws + 54525952L;
    short* W2T = ws + 58720256L;
    short* hb  = ws + 16777216L;  // [16M,48M) — xb/VTb/ctx dead by FFN1
    short* ao  = ws + 0L;         // reuses Qb (dead after attn)
    short* x1  = ws + 8388608L;   // reuses Kbf (dead after attn)
    short* ffn = ws + 0L;         // reuses ao (dead after ln1)

    dim3 blk(256);

    // x -> bf16
    cvt_f2b_k<<<2048, blk, 0, stream>>>(x, xb, (long)M_ * D_);

    // Weight transposes (fp32 -> bf16), everything becomes [N][K] k-contiguous
    transpose_k<float><<<dim3(2, 32, 16),  blk, 0, stream>>>(Wq, WqT, 1024, 64,   0, 65536, 65536);
    transpose_k<float><<<dim3(2, 32, 16),  blk, 0, stream>>>(Wk, WkT, 1024, 64,   0, 65536, 65536);
    transpose_k<float><<<dim3(2, 32, 16),  blk, 0, stream>>>(Wv, WvT, 1024, 64,   0, 65536, 65536);
    transpose_k<float><<<dim3(32, 32, 1),  blk, 0, stream>>>(Wo, WoT, 1024, 1024, 0, 0, 0);
    transpose_k<float><<<dim3(128, 32, 1), blk, 0, stream>>>(W1, W1T, 1024, 4096, 0, 0, 0);
    transpose_k<float><<<dim3(32, 128, 1), blk, 0, stream>>>(W2, W2T, 4096, 1024, 0, 0, 0);

    // QKV projections; Q folds softmax scale IN EXP2 DOMAIN: 0.125*log2(e)
    gemm_k<<<dim3(8, 64), blk, 0, stream>>>(xb, WqT, bq, Qb,  M_, 1024, 1024, 0.18033688011112042f, 0);
    gemm_k<<<dim3(8, 64), blk, 0, stream>>>(xb, WkT, bk, Kbf, M_, 1024, 1024, 1.0f, 0);
    gemm_k<<<dim3(8, 64), blk, 0, stream>>>(xb, WvT, bv, Vbf, M_, 1024, 1024, 1.0f, 0);

    // V -> V^T per (b,h): [2048 s][64 e] -> [64 e][2048 s]
    transpose_k<short><<<dim3(2, 64, 64), blk, 0, stream>>>(Vbf, VTb, 2048, 1024, 2097152, 64, 131072);

    // flash attention
    attn_k<<<dim3(32, 64), blk, 0, stream>>>(Qb, Kbf, VTb, ctx);

    // out projection + residual LN (residual from ORIGINAL fp32 x)
    gemm_k<<<dim3(8, 64), blk, 0, stream>>>(ctx, WoT, bo, ao, M_, 1024, 1024, 1.0f, 0);
    ln_k<1,0><<<8192, blk, 0, stream>>>(x, ao, g1, be1, x1);

    // FFN
    gemm_k<<<dim3(32, 64), blk, 0, stream>>>(x1, W1T, b1, hb,  M_, 4096, 1024, 1.0f, 1);
    gemm_k<<<dim3(8, 64),  blk, 0, stream>>>(hb, W2T, b2, ffn, M_, 1024, 4096, 1.0f, 0);

    // final LN -> fp32 d_out
    ln_k<0,1><<<8192, blk, 0, stream>>>(x1, ffn, g2, be2, d_out);
}

// Round 8
// 597.581 us; speedup vs baseline: 1.0558x; 1.0343x over previous
//
#include <hip/hip_runtime.h>

// Problem constants
#define B_ 4
#define S_ 2048
#define D_ 1024
#define H_ 16
#define HD_ 64
#define F_ 4096
#define M_ (B_*S_)   // 8192 tokens

// dtypes (established r2-r6): d_in = float32, d_out = float32.

typedef __attribute__((ext_vector_type(8))) short bf16x8;   // 8 bf16 (4 VGPR) MFMA A/B frag
typedef __attribute__((ext_vector_type(4))) short short4_t; // 4 bf16 (8B)
typedef __attribute__((ext_vector_type(4))) float f32x4;    // MFMA C/D frag

#define AS1q __attribute__((address_space(1)))
#define AS3q __attribute__((address_space(3)))

__device__ __forceinline__ float bf2f(short u) {
    union { unsigned int i; float f; } v;
    v.i = ((unsigned int)(unsigned short)u) << 16;
    return v.f;
}
__device__ __forceinline__ short f2bf(float f) {
    union { float f; unsigned int i; } v; v.f = f;
    unsigned int r = v.i + 0x7fffu + ((v.i >> 16) & 1u);  // RNE
    return (short)(r >> 16);
}
__device__ __forceinline__ void gld_lds16(const short* g, short* l) {
    __builtin_amdgcn_global_load_lds((const AS1q void*)g, (AS3q void*)l, 16, 0, 0);
}

// ---------------------------------------------------------------------------
// fp32 -> bf16 convert (grid-stride, float4 loads)
// ---------------------------------------------------------------------------
__global__ __launch_bounds__(256) void cvt_f2b_k(
    const float* __restrict__ in, short* __restrict__ out, long n)
{
    long i = ((long)blockIdx.x * 256 + threadIdx.x) * 4;
    long stride = (long)gridDim.x * 256 * 4;
    for (; i < n; i += stride) {
        float4 v = *(const float4*)(in + i);
        short4_t o;
        o[0] = f2bf(v.x); o[1] = f2bf(v.y); o[2] = f2bf(v.z); o[3] = f2bf(v.w);
        *(short4_t*)(out + i) = o;
    }
}

// ---------------------------------------------------------------------------
// Tiled transpose: out[z][c][r] = cvt(in[base(z) + r*in_rstride + c])
// ---------------------------------------------------------------------------
template<typename TI>
__global__ __launch_bounds__(256) void transpose_k(
    const TI* __restrict__ in, short* __restrict__ out,
    int rows, long in_rstride,
    long in_bstrideB, long in_bstrideH, long out_bstride)
{
    __shared__ short tile[32][33];
    int z = blockIdx.z;
    const TI* ip = in + (long)(z >> 4) * in_bstrideB + (long)(z & 15) * in_bstrideH;
    short* op = out + (long)z * out_bstride;
    int r0 = blockIdx.y * 32, c0 = blockIdx.x * 32;
    int tx = threadIdx.x & 31, ty = threadIdx.x >> 5;   // ty 0..7
#pragma unroll
    for (int i = 0; i < 32; i += 8) {
        TI v = ip[(long)(r0 + ty + i) * in_rstride + (c0 + tx)];
        if constexpr (sizeof(TI) == 4) tile[ty + i][tx] = f2bf((float)v);
        else                           tile[ty + i][tx] = (short)v;
    }
    __syncthreads();
#pragma unroll
    for (int i = 0; i < 32; i += 8)
        op[(long)(c0 + ty + i) * rows + (r0 + tx)] = tile[tx][ty + i];
}

// ---------------------------------------------------------------------------
// GEMM (m97 structure + XCD swizzle): C = act((A @ BT^T + bias) * scale)
// 128x128 tile, BK=32, 4 waves, global_load_lds width-16 staging, linear LDS.
// ---------------------------------------------------------------------------
__global__ __launch_bounds__(256) void gemm_k(
    const short* __restrict__ A,    // [M][K] bf16
    const short* __restrict__ BT,   // [N][K] bf16
    const float* __restrict__ bias, // [N] fp32
    short* __restrict__ C,          // [M][N] bf16
    int M, int N, int K, float scale, int relu)
{
    __shared__ short Alds[128*32];   // linear, no pad (global_load_lds constraint)
    __shared__ short Blds[128*32];
    int tid = threadIdx.x;
    int wave = tid >> 6, lane = tid & 63;
    int lgrp = lane >> 4, lrow = lane & 15;
    int wr = wave >> 1, wc = wave & 1;
    // XCD-aware block swizzle (bijective: nwg % 8 == 0 for all our grids)
    int gx = gridDim.x;
    int nwg = gx * gridDim.y;
    int lin = blockIdx.y * gx + blockIdx.x;
    int nid = (lin & 7) * (nwg >> 3) + (lin >> 3);
    int bm = (nid / gx) * 128, bn = (nid % gx) * 128;

    int srow = wave * 32 + (lane >> 2);
    int scol = (lane & 3) * 8;
    const short* gA = A  + (long)(bm + srow) * K + scol;
    const short* gB = BT + (long)(bn + srow) * K + scol;
    short* lA0 = &Alds[(wave * 32) * 32];
    short* lA1 = &Alds[(wave * 32 + 16) * 32];
    short* lB0 = &Blds[(wave * 32) * 32];
    short* lB1 = &Blds[(wave * 32 + 16) * 32];
    long k16 = 16L * K;

    f32x4 acc[4][4] = {};
    for (int k0 = 0; k0 < K; k0 += 32) {
        gld_lds16(gA + k0,       lA0);
        gld_lds16(gA + k0 + k16, lA1);
        gld_lds16(gB + k0,       lB0);
        gld_lds16(gB + k0 + k16, lB1);
        __syncthreads();
        bf16x8 af[4], bv[4];
#pragma unroll
        for (int i = 0; i < 4; i++) {
            af[i] = *(const bf16x8*)&Alds[(wr*64 + i*16 + lrow) * 32 + 8*lgrp];
            bv[i] = *(const bf16x8*)&Blds[(wc*64 + i*16 + lrow) * 32 + 8*lgrp];
        }
#pragma unroll
        for (int mi = 0; mi < 4; mi++)
#pragma unroll
            for (int ni = 0; ni < 4; ni++)
                acc[mi][ni] = __builtin_amdgcn_mfma_f32_16x16x32_bf16(
                    af[mi], bv[ni], acc[mi][ni], 0, 0, 0);
        __syncthreads();
    }
#pragma unroll
    for (int ni = 0; ni < 4; ni++) {
        int col = bn + wc*64 + ni*16 + lrow;
        float bb = bias[col];
#pragma unroll
        for (int mi = 0; mi < 4; mi++) {
#pragma unroll
            for (int j = 0; j < 4; j++) {
                int row = bm + wr*64 + mi*16 + lgrp*4 + j;
                float v = (acc[mi][ni][j] + bb) * scale;
                if (relu) v = fmaxf(v, 0.0f);
                C[(long)row * N + col] = f2bf(v);
            }
        }
    }
}

// ---------------------------------------------------------------------------
// Flash attention v3: NO K/V LDS staging (K/V are L2-resident per (b,h):
// 256 KB each), NO barriers. 4 waves x 32 q-rows = 128 q-rows/block,
// grid (16,64) + XCD swizzle. Defer-max (THR=8, exp2 domain) + deferred
// lane-partial sum: zero cross-lane ops per tile on the common path.
// Q pre-scaled by 0.125*log2(e). Only LDS: wave-private P round-trip (9 KB).
// ---------------------------------------------------------------------------
__global__ __launch_bounds__(256) void attn_k(
    const short* __restrict__ Q,   // [M][1024], scaled
    const short* __restrict__ Kb,  // [M][1024]
    const short* __restrict__ VT,  // [64][64][2048]
    short* __restrict__ O)         // [M][1024]
{
    __shared__ short Plds[4][16][72];
    // XCD swizzle: 1024 blocks -> each XCD gets 128 contiguous (8 full bh)
    int lin = blockIdx.y * 16 + blockIdx.x;
    int nid = (lin & 7) * 128 + (lin >> 3);
    int bh = nid >> 4, qt = nid & 15;
    int b = bh >> 4, h = bh & 15;
    int q0 = qt * 128;
    int tid = threadIdx.x, wave = tid >> 6, lane = tid & 63;
    int lgrp = lane >> 4, lrow = lane & 15;

    // Q fragments: 2 row-blocks x K=64 (2 kk)
    bf16x8 aq[2][2];
    {
        const short* qp = Q + (long)(b*S_ + q0 + wave*32) * 1024 + h*64;
#pragma unroll
        for (int rb = 0; rb < 2; rb++)
#pragma unroll
            for (int kk = 0; kk < 2; kk++)
                aq[rb][kk] = *(const bf16x8*)(qp + (long)(rb*16 + lrow)*1024 + kk*32 + 8*lgrp);
    }

    f32x4 accO[2][4] = {};
    float mj[2][4], ls[2][4];
#pragma unroll
    for (int rb = 0; rb < 2; rb++)
#pragma unroll
        for (int j = 0; j < 4; j++) { mj[rb][j] = -1e30f; ls[rb][j] = 0.f; }

    const short* kbp = Kb + (long)(b*S_) * 1024 + h*64;   // + key*1024 + e
    const short* vbp = VT + (long)bh * (64L*S_);          // + e*2048 + key

    for (int kb = 0; kb < S_; kb += 64) {
        // K fragments (B-operand), direct from L2: key = cb*16+lrow
        bf16x8 bk[4][2];
#pragma unroll
        for (int cb = 0; cb < 4; cb++)
#pragma unroll
            for (int kk = 0; kk < 2; kk++)
                bk[cb][kk] = *(const bf16x8*)(kbp + (long)(kb + cb*16 + lrow)*1024 + kk*32 + 8*lgrp);
        // V fragments (B-operand for PV), direct from L2: e = eb*16+lrow
        bf16x8 bvv[4][2];
#pragma unroll
        for (int eb = 0; eb < 4; eb++)
#pragma unroll
            for (int kk = 0; kk < 2; kk++)
                bvv[eb][kk] = *(const bf16x8*)(vbp + (long)(eb*16 + lrow)*S_ + kb + kk*32 + 8*lgrp);

        // QK^T: C[row=q(lgrp*4+j)][col=key(cb*16+lrow)]
        f32x4 accs[2][4] = {};
        __builtin_amdgcn_s_setprio(1);
#pragma unroll
        for (int rb = 0; rb < 2; rb++)
#pragma unroll
            for (int cb = 0; cb < 4; cb++)
#pragma unroll
                for (int kk = 0; kk < 2; kk++)
                    accs[rb][cb] = __builtin_amdgcn_mfma_f32_16x16x32_bf16(
                        aq[rb][kk], bk[cb][kk], accs[rb][cb], 0, 0, 0);
        __builtin_amdgcn_s_setprio(0);

        // defer-max online softmax (exp2 domain)
        int ok = 1;
        float mx[2][4];
#pragma unroll
        for (int rb = 0; rb < 2; rb++)
#pragma unroll
            for (int j = 0; j < 4; j++) {
                float m4 = fmaxf(fmaxf(accs[rb][0][j], accs[rb][1][j]),
                                 fmaxf(accs[rb][2][j], accs[rb][3][j]));
                mx[rb][j] = m4;
                ok &= (m4 <= mj[rb][j] + 8.0f);
            }
        if (!__all(ok)) {   // rare: refresh row max, rescale state
#pragma unroll
            for (int rb = 0; rb < 2; rb++)
#pragma unroll
                for (int j = 0; j < 4; j++) {
                    float m2 = mx[rb][j];
#pragma unroll
                    for (int off = 1; off < 16; off <<= 1)
                        m2 = fmaxf(m2, __shfl_xor(m2, off));
                    float mnew = fmaxf(mj[rb][j], m2);
                    float al = exp2f(mj[rb][j] - mnew);
                    mj[rb][j] = mnew;
                    ls[rb][j] *= al;
#pragma unroll
                    for (int eb = 0; eb < 4; eb++) accO[rb][eb][j] *= al;
                }
        }
#pragma unroll
        for (int rb = 0; rb < 2; rb++)
#pragma unroll
            for (int j = 0; j < 4; j++) {
                float p0 = exp2f(accs[rb][0][j] - mj[rb][j]);
                float p1 = exp2f(accs[rb][1][j] - mj[rb][j]);
                float p2 = exp2f(accs[rb][2][j] - mj[rb][j]);
                float p3 = exp2f(accs[rb][3][j] - mj[rb][j]);
                accs[rb][0][j] = p0; accs[rb][1][j] = p1;
                accs[rb][2][j] = p2; accs[rb][3][j] = p3;
                ls[rb][j] += (p0 + p1) + (p2 + p3);   // lane-partial; reduced once at end
            }

        // P round-trip (wave-private LDS) + PV, per row-block
#pragma unroll
        for (int rb = 0; rb < 2; rb++) {
#pragma unroll
            for (int cb = 0; cb < 4; cb++)
#pragma unroll
                for (int j = 0; j < 4; j++)
                    Plds[wave][lgrp*4 + j][cb*16 + lrow] = f2bf(accs[rb][cb][j]);
            bf16x8 ap0 = *(const bf16x8*)&Plds[wave][lrow][8*lgrp];
            bf16x8 ap1 = *(const bf16x8*)&Plds[wave][lrow][32 + 8*lgrp];
            __builtin_amdgcn_s_setprio(1);
#pragma unroll
            for (int eb = 0; eb < 4; eb++) {
                accO[rb][eb] = __builtin_amdgcn_mfma_f32_16x16x32_bf16(ap0, bvv[eb][0], accO[rb][eb], 0, 0, 0);
                accO[rb][eb] = __builtin_amdgcn_mfma_f32_16x16x32_bf16(ap1, bvv[eb][1], accO[rb][eb], 0, 0, 0);
            }
            __builtin_amdgcn_s_setprio(0);
        }
    }

    // epilogue: single cross-lane sum reduce, then normalized store
#pragma unroll
    for (int rb = 0; rb < 2; rb++)
#pragma unroll
        for (int j = 0; j < 4; j++) {
            float s = ls[rb][j];
#pragma unroll
            for (int off = 1; off < 16; off <<= 1)
                s += __shfl_xor(s, off);
            ls[rb][j] = 1.0f / s;
        }
#pragma unroll
    for (int rb = 0; rb < 2; rb++)
#pragma unroll
        for (int eb = 0; eb < 4; eb++)
#pragma unroll
            for (int j = 0; j < 4; j++) {
                int qr = q0 + wave*32 + rb*16 + lgrp*4 + j;
                O[(long)(b*S_ + qr)*1024 + h*64 + eb*16 + lrow] =
                    f2bf(accO[rb][eb][j] * ls[rb][j]);
            }
}

// ---------------------------------------------------------------------------
// Residual + LayerNorm: O[row] = LN(X[row] + Y[row]) * g + be   (D=1024)
// ---------------------------------------------------------------------------
template<int XF32, int OUTF32>
__global__ __launch_bounds__(256) void ln_k(
    const void* __restrict__ Xv, const short* __restrict__ Y,
    const float* __restrict__ g, const float* __restrict__ be,
    void* __restrict__ Ov)
{
    int row = blockIdx.x, tid = threadIdx.x;
    long base = (long)row * 1024 + tid * 4;
    float a[4];
    if constexpr (XF32) {
        float4 xv = *(const float4*)((const float*)Xv + base);
        a[0] = xv.x; a[1] = xv.y; a[2] = xv.z; a[3] = xv.w;
    } else {
        short4_t xv = *(const short4_t*)((const short*)Xv + base);
#pragma unroll
        for (int j = 0; j < 4; j++) a[j] = bf2f(xv[j]);
    }
    short4_t yv = *(const short4_t*)(Y + base);
    float s = 0.f, s2 = 0.f;
#pragma unroll
    for (int j = 0; j < 4; j++) {
        a[j] += bf2f(yv[j]);
        s += a[j]; s2 += a[j] * a[j];
    }
#pragma unroll
    for (int off = 32; off >= 1; off >>= 1) {
        s  += __shfl_xor(s, off);
        s2 += __shfl_xor(s2, off);
    }
    __shared__ float red[8];
    if ((tid & 63) == 0) { red[(tid >> 6)*2] = s; red[(tid >> 6)*2 + 1] = s2; }
    __syncthreads();
    s  = red[0] + red[2] + red[4] + red[6];
    s2 = red[1] + red[3] + red[5] + red[7];
    float mean = s * (1.0f/1024.0f);
    float var  = s2 * (1.0f/1024.0f) - mean*mean;
    float rstd = rsqrtf(var + 1e-5f);
    float4 gv = *(const float4*)(g  + tid*4);
    float4 bv = *(const float4*)(be + tid*4);
    float r0 = (a[0] - mean) * rstd * gv.x + bv.x;
    float r1 = (a[1] - mean) * rstd * gv.y + bv.y;
    float r2 = (a[2] - mean) * rstd * gv.z + bv.z;
    float r3 = (a[3] - mean) * rstd * gv.w + bv.w;
    if constexpr (OUTF32) {
        *(float4*)((float*)Ov + base) = make_float4(r0, r1, r2, r3);
    } else {
        short4_t ov;
        ov[0] = f2bf(r0); ov[1] = f2bf(r1); ov[2] = f2bf(r2); ov[3] = f2bf(r3);
        *(short4_t*)((short*)Ov + base) = ov;
    }
}

// ---------------------------------------------------------------------------
extern "C" void kernel_launch(void* const* d_in, const int* in_sizes, int n_in,
                              void* d_out, int out_size, void* d_ws, size_t ws_size,
                              hipStream_t stream)
{
    static const int ins[17] = {0,1,2,3,4,5,6,7,8,9,10,11,12,13,14,15,16};
    static const int srt[17] = {16,4,12,2,10,5,13,3,11,0,6,1,7,14,8,15,9};
    const int* IX = (in_sizes[0] == 8388608) ? ins : srt;

    const float* x   = (const float*)d_in[IX[0]];
    const float* Wq  = (const float*)d_in[IX[1]];
    const float* bq  = (const float*)d_in[IX[2]];
    const float* Wk  = (const float*)d_in[IX[3]];
    const float* bk  = (const float*)d_in[IX[4]];
    const float* Wv  = (const float*)d_in[IX[5]];
    const float* bv  = (const float*)d_in[IX[6]];
    const float* Wo  = (const float*)d_in[IX[7]];
    const float* bo  = (const float*)d_in[IX[8]];
    const float* W1  = (const float*)d_in[IX[9]];
    const float* b1  = (const float*)d_in[IX[10]];
    const float* W2  = (const float*)d_in[IX[11]];
    const float* b2  = (const float*)d_in[IX[12]];
    const float* g1  = (const float*)d_in[IX[13]];
    const float* be1 = (const float*)d_in[IX[14]];
    const float* g2  = (const float*)d_in[IX[15]];
    const float* be2 = (const float*)d_in[IX[16]];
    short* ws  = (short*)d_ws;

    // Compact workspace overlay (short-element offsets). Peak = 126 MB.
    short* Qb  = ws + 0L;
    short* Kbf = ws + 8388608L;
    short* xb  = ws + 16777216L;
    short* VTb = ws + 25165824L;
    short* ctx = ws + 33554432L;
    short* WqT = ws + 41943040L;
    short* WkT = ws + 42991616L;
    short* WvT = ws + 44040192L;
    short* WoT = ws + 45088768L;
    short* Vbf = ws + 46137344L;
    short* W1T = ws + 54525952L;
    short* W2T = ws + 58720256L;
    short* hb  = ws + 16777216L;  // [16M,48M) — xb/VTb/ctx dead by FFN1
    short* ao  = ws + 0L;         // reuses Qb (dead after attn)
    short* x1  = ws + 8388608L;   // reuses Kbf (dead after attn)
    short* ffn = ws + 0L;         // reuses ao (dead after ln1)

    dim3 blk(256);

    cvt_f2b_k<<<2048, blk, 0, stream>>>(x, xb, (long)M_ * D_);

    transpose_k<float><<<dim3(2, 32, 16),  blk, 0, stream>>>(Wq, WqT, 1024, 64,   0, 65536, 65536);
    transpose_k<float><<<dim3(2, 32, 16),  blk, 0, stream>>>(Wk, WkT, 1024, 64,   0, 65536, 65536);
    transpose_k<float><<<dim3(2, 32, 16),  blk, 0, stream>>>(Wv, WvT, 1024, 64,   0, 65536, 65536);
    transpose_k<float><<<dim3(32, 32, 1),  blk, 0, stream>>>(Wo, WoT, 1024, 1024, 0, 0, 0);
    transpose_k<float><<<dim3(128, 32, 1), blk, 0, stream>>>(W1, W1T, 1024, 4096, 0, 0, 0);
    transpose_k<float><<<dim3(32, 128, 1), blk, 0, stream>>>(W2, W2T, 4096, 1024, 0, 0, 0);

    // QKV projections; Q folds softmax scale IN EXP2 DOMAIN: 0.125*log2(e)
    gemm_k<<<dim3(8, 64), blk, 0, stream>>>(xb, WqT, bq, Qb,  M_, 1024, 1024, 0.18033688011112042f, 0);
    gemm_k<<<dim3(8, 64), blk, 0, stream>>>(xb, WkT, bk, Kbf, M_, 1024, 1024, 1.0f, 0);
    gemm_k<<<dim3(8, 64), blk, 0, stream>>>(xb, WvT, bv, Vbf, M_, 1024, 1024, 1.0f, 0);

    // V -> V^T per (b,h): [2048 s][64 e] -> [64 e][2048 s]
    transpose_k<short><<<dim3(2, 64, 64), blk, 0, stream>>>(Vbf, VTb, 2048, 1024, 2097152, 64, 131072);

    // flash attention (no-LDS-staging variant)
    attn_k<<<dim3(16, 64), blk, 0, stream>>>(Qb, Kbf, VTb, ctx);

    // out projection + residual LN (residual from ORIGINAL fp32 x)
    gemm_k<<<dim3(8, 64), blk, 0, stream>>>(ctx, WoT, bo, ao, M_, 1024, 1024, 1.0f, 0);
    ln_k<1,0><<<8192, blk, 0, stream>>>(x, ao, g1, be1, x1);

    // FFN
    gemm_k<<<dim3(32, 64), blk, 0, stream>>>(x1, W1T, b1, hb,  M_, 4096, 1024, 1.0f, 1);
    gemm_k<<<dim3(8, 64),  blk, 0, stream>>>(hb, W2T, b2, ffn, M_, 1024, 4096, 1.0f, 0);

    ln_k<0,1><<<8192, blk, 0, stream>>>(x1, ffn, g2, be2, d_out);
}